// Round 2
// baseline (585.232 us; speedup 1.0000x reference)
//
#include <hip/hip_runtime.h>

// Transformer-XL relative multi-head attention, MI355X (gfx950).
// Round 1: resubmit of Round-0 (infra timeout; no bench data yet).
// Correctness-first full-MFMA pipeline (fp16 data, f32 accum).
//
// Pipeline:
//   pack:   f32 -> f16 (x, pos, 5 weights), concat(mem,x) -> Kin
//   gemm:   Q(dual out +r_w_bias/+r_r_bias), K, V, R projections  [128x128 tile MFMA]
//   gemm:   BD[z=b*16+n][i][u] = Qr_i . R_u   (K=64, per-head strided)
//   attn:   flash-style, S = Qw.K^T + BD[i][j+QLEN-1-i], mask j<=i+MLEN, online softmax, PV
//   gemm:   out = AV . Wo^T (f32 out)

#define B_SZ 2
#define QLEN 1024
#define MLEN 1024
#define KLEN 2048
#define DMODEL 1024
#define NH 16
#define DH 64

typedef _Float16 f16;
typedef __attribute__((ext_vector_type(8))) _Float16 f16x8;
typedef __attribute__((ext_vector_type(4))) _Float16 f16x4;
typedef __attribute__((ext_vector_type(4))) float f32x4;

__device__ __forceinline__ f16 f2h(float v) { return (f16)v; }
__device__ __forceinline__ float h2f(f16 v) { return (float)v; }

__device__ __forceinline__ f32x4 mfma16(f16x8 a, f16x8 b, f32x4 c) {
  return __builtin_amdgcn_mfma_f32_16x16x32_f16(a, b, c, 0, 0, 0);
}

// ---------------- pack ----------------
__global__ __launch_bounds__(256) void convert_kernel(const float* __restrict__ src,
                                                      f16* __restrict__ dst, int n4) {
  const int i = blockIdx.x * 256 + threadIdx.x;
  if (i >= n4) return;
  const float4 v = reinterpret_cast<const float4*>(src)[i];
  f16x4 o = {(f16)v.x, (f16)v.y, (f16)v.z, (f16)v.w};
  reinterpret_cast<f16x4*>(dst)[i] = o;
}

__global__ __launch_bounds__(256) void build_kin_kernel(const float* __restrict__ x,
                                                        const float* __restrict__ mem,
                                                        f16* __restrict__ kin) {
  const int i = blockIdx.x * 256 + threadIdx.x;  // one 4-elem chunk
  const int per_b = KLEN * DMODEL / 4;
  const int b = i / per_b;
  const int rem = i - b * per_b;
  const int row = rem / (DMODEL / 4);
  const int cc = (rem - row * (DMODEL / 4)) * 4;
  const float* src = (row < MLEN)
      ? mem + ((size_t)b * MLEN + row) * DMODEL + cc
      : x + ((size_t)b * QLEN + (row - MLEN)) * DMODEL + cc;
  const float4 v = *reinterpret_cast<const float4*>(src);
  f16x4 o = {(f16)v.x, (f16)v.y, (f16)v.z, (f16)v.w};
  *reinterpret_cast<f16x4*>(kin + (size_t)i * 4) = o;
}

// ---------------- GEMM: C[M,N] = A[M,K] . B[N,K]^T ----------------
// 128x128 tile, 4 waves (2x2 of 64x64), BK=32, padded LDS (row stride 40 f16).
// DUAL: write C0=acc+bias0, C1=acc+bias1 (f16). OUT_F32: C0 is float.
// BD_MODE: blockIdx.z = b*16+n; A,B offset to head slice; C offset to BD[z].
template <int DUAL, int OUT_F32, int BD_MODE>
__global__ __launch_bounds__(256) void gemm_bt_kernel(
    const f16* __restrict__ A, const f16* __restrict__ B,
    void* __restrict__ C0v, void* __restrict__ C1v,
    const float* __restrict__ bias0, const float* __restrict__ bias1,
    int M, int N, int K, int lda, int ldb, int ldc) {
  if constexpr (BD_MODE) {
    const int z = blockIdx.z, bb = z >> 4, nn = z & 15;
    A += (size_t)bb * QLEN * lda + nn * DH;
    B += nn * DH;
    C0v = (void*)((f16*)C0v + (size_t)z * QLEN * KLEN);
  }
  const int bm = blockIdx.y * 128, bn = blockIdx.x * 128;
  const int tid = threadIdx.x;
  const int wave = tid >> 6, lane = tid & 63;
  const int wr = wave >> 1, wc = wave & 1;
  const int lr = lane & 15, hi = lane >> 4;

  __shared__ f16 As[128][40];
  __shared__ f16 Bs[128][40];

  f32x4 acc[4][4];
#pragma unroll
  for (int m = 0; m < 4; ++m)
#pragma unroll
    for (int n = 0; n < 4; ++n) acc[m][n] = f32x4{0.f, 0.f, 0.f, 0.f};

  for (int k0 = 0; k0 < K; k0 += 32) {
#pragma unroll
    for (int it = 0; it < 2; ++it) {
      const int c = it * 256 + tid;
      const int row = c >> 2, col8 = (c & 3) << 3;
      *reinterpret_cast<f16x8*>(&As[row][col8]) =
          *reinterpret_cast<const f16x8*>(&A[(size_t)(bm + row) * lda + k0 + col8]);
      *reinterpret_cast<f16x8*>(&Bs[row][col8]) =
          *reinterpret_cast<const f16x8*>(&B[(size_t)(bn + row) * ldb + k0 + col8]);
    }
    __syncthreads();
    f16x8 af[4], bf[4];
#pragma unroll
    for (int m = 0; m < 4; ++m)
      af[m] = *reinterpret_cast<const f16x8*>(&As[wr * 64 + m * 16 + lr][hi * 8]);
#pragma unroll
    for (int n = 0; n < 4; ++n)
      bf[n] = *reinterpret_cast<const f16x8*>(&Bs[wc * 64 + n * 16 + lr][hi * 8]);
#pragma unroll
    for (int m = 0; m < 4; ++m)
#pragma unroll
      for (int n = 0; n < 4; ++n)
        acc[m][n] = mfma16(af[m], bf[n], acc[m][n]);
    __syncthreads();
  }

#pragma unroll
  for (int m = 0; m < 4; ++m)
#pragma unroll
    for (int n = 0; n < 4; ++n)
#pragma unroll
      for (int r = 0; r < 4; ++r) {
        const int grow = bm + wr * 64 + m * 16 + hi * 4 + r;
        const int gcol = bn + wc * 64 + n * 16 + lr;
        const float v = acc[m][n][r];
        if constexpr (OUT_F32) {
          reinterpret_cast<float*>(C0v)[(size_t)grow * ldc + gcol] = v;
        } else if constexpr (DUAL) {
          reinterpret_cast<f16*>(C0v)[(size_t)grow * ldc + gcol] = f2h(v + bias0[gcol]);
          reinterpret_cast<f16*>(C1v)[(size_t)grow * ldc + gcol] = f2h(v + bias1[gcol]);
        } else {
          reinterpret_cast<f16*>(C0v)[(size_t)grow * ldc + gcol] = f2h(v);
        }
      }
}

// ---------------- attention ----------------
// Block: 256 threads = 4 waves; block owns (b, head, 128 q-rows); wave owns 32 rows.
// Per j-tile (64 keys): stage K[64][64] (row-major) and V^T[64][64] in LDS,
// S = Qw.K^T via MFMA, add shifted-BD + scale + mask, per-row online softmax
// (16-lane shfl groups), P->LDS (per-wave), O += P.V via MFMA.
__global__ __launch_bounds__(256) void attn_kernel(
    const f16* __restrict__ Qw, const f16* __restrict__ Kb,
    const f16* __restrict__ Vb, const f16* __restrict__ BD,
    f16* __restrict__ AV) {
  const int qb = blockIdx.x * 128;
  const int n = blockIdx.y;
  const int b = blockIdx.z;
  const int tid = threadIdx.x;
  const int wave = tid >> 6, lane = tid & 63;
  const int lr = lane & 15, hi = lane >> 4;

  __shared__ f16 Ks[64][72];       // [j][d]
  __shared__ f16 Vs[64][72];       // transposed: [d][j]
  __shared__ f16 Ps[4][32][72];    // per-wave P tile

  f16x8 qf[2][2];
  {
    const size_t qbase = ((size_t)(b * QLEN + qb + wave * 32)) * DMODEL + n * DH;
#pragma unroll
    for (int m = 0; m < 2; ++m)
#pragma unroll
      for (int kk = 0; kk < 2; ++kk)
        qf[m][kk] = *reinterpret_cast<const f16x8*>(
            &Qw[qbase + (size_t)(m * 16 + lr) * DMODEL + kk * 32 + hi * 8]);
  }

  f32x4 o[2][4];
#pragma unroll
  for (int m = 0; m < 2; ++m)
#pragma unroll
    for (int d = 0; d < 4; ++d) o[m][d] = f32x4{0.f, 0.f, 0.f, 0.f};
  float mrow[2][4], lrow[2][4];
#pragma unroll
  for (int m = 0; m < 2; ++m)
#pragma unroll
    for (int r = 0; r < 4; ++r) { mrow[m][r] = -1e30f; lrow[m][r] = 0.f; }

  const f16* bdz = BD + ((size_t)(b * NH + n)) * QLEN * KLEN;
  const int jtiles = (qb + 128 + MLEN) >> 6;

  for (int jt = 0; jt < jtiles; ++jt) {
    const int j0 = jt << 6;
    const size_t kvbase = ((size_t)(b * KLEN + j0)) * DMODEL + n * DH;
#pragma unroll
    for (int it = 0; it < 2; ++it) {
      const int c = it * 256 + tid;
      // K: coalesced global read, row-major LDS write
      const int krow = c >> 3, kcol8 = (c & 7) << 3;
      *reinterpret_cast<f16x8*>(&Ks[krow][kcol8]) =
          *reinterpret_cast<const f16x8*>(&Kb[kvbase + (size_t)krow * DMODEL + kcol8]);
      // V: lane-per-row mapping -> conflict-free transposed LDS write
      const int vrow = c & 63, vcol8 = ((c >> 6) & 7) << 3;
      const f16x8 vv =
          *reinterpret_cast<const f16x8*>(&Vb[kvbase + (size_t)vrow * DMODEL + vcol8]);
#pragma unroll
      for (int e = 0; e < 8; ++e) Vs[vcol8 + e][vrow] = vv[e];
    }
    __syncthreads();

    f32x4 s[2][4];
#pragma unroll
    for (int m = 0; m < 2; ++m)
#pragma unroll
      for (int nf = 0; nf < 4; ++nf) s[m][nf] = f32x4{0.f, 0.f, 0.f, 0.f};
#pragma unroll
    for (int kk = 0; kk < 2; ++kk)
#pragma unroll
      for (int nf = 0; nf < 4; ++nf) {
        const f16x8 bfr =
            *reinterpret_cast<const f16x8*>(&Ks[nf * 16 + lr][kk * 32 + hi * 8]);
#pragma unroll
        for (int m = 0; m < 2; ++m) s[m][nf] = mfma16(qf[m][kk], bfr, s[m][nf]);
      }

    // add shifted BD, scale, mask
    float sv[2][4][4];
#pragma unroll
    for (int m = 0; m < 2; ++m)
#pragma unroll
      for (int r = 0; r < 4; ++r) {
        const int i = qb + wave * 32 + m * 16 + hi * 4 + r;
        const size_t bdrow = (size_t)i * KLEN + (QLEN - 1 - i);
#pragma unroll
        for (int nf = 0; nf < 4; ++nf) {
          const int j = j0 + nf * 16 + lr;
          sv[m][nf][r] = (j <= i + MLEN)
                             ? (s[m][nf][r] + h2f(bdz[bdrow + j])) * 0.125f
                             : -1e30f;
        }
      }

    // online softmax per row (row lives on 16 lanes sharing hi)
#pragma unroll
    for (int m = 0; m < 2; ++m)
#pragma unroll
      for (int r = 0; r < 4; ++r) {
        float tmax = fmaxf(fmaxf(sv[m][0][r], sv[m][1][r]),
                           fmaxf(sv[m][2][r], sv[m][3][r]));
#pragma unroll
        for (int d = 1; d < 16; d <<= 1) tmax = fmaxf(tmax, __shfl_xor(tmax, d, 64));
        const float mnew = fmaxf(mrow[m][r], tmax);
        const float alpha = __expf(mrow[m][r] - mnew);
        mrow[m][r] = mnew;
        float tsum = 0.f;
#pragma unroll
        for (int nf = 0; nf < 4; ++nf) {
          const float p = __expf(sv[m][nf][r] - mnew);
          sv[m][nf][r] = p;
          tsum += p;
        }
#pragma unroll
        for (int d = 1; d < 16; d <<= 1) tsum += __shfl_xor(tsum, d, 64);
        lrow[m][r] = lrow[m][r] * alpha + tsum;
#pragma unroll
        for (int df = 0; df < 4; ++df) o[m][df][r] *= alpha;
      }

    // P -> per-wave LDS (f32->f16), then O += P.V
#pragma unroll
    for (int m = 0; m < 2; ++m)
#pragma unroll
      for (int nf = 0; nf < 4; ++nf)
#pragma unroll
        for (int r = 0; r < 4; ++r)
          Ps[wave][m * 16 + hi * 4 + r][nf * 16 + lr] = f2h(sv[m][nf][r]);

#pragma unroll
    for (int kk = 0; kk < 2; ++kk)
#pragma unroll
      for (int m = 0; m < 2; ++m) {
        const f16x8 pa =
            *reinterpret_cast<const f16x8*>(&Ps[wave][m * 16 + lr][kk * 32 + hi * 8]);
#pragma unroll
        for (int df = 0; df < 4; ++df) {
          const f16x8 vb =
              *reinterpret_cast<const f16x8*>(&Vs[df * 16 + lr][kk * 32 + hi * 8]);
          o[m][df] = mfma16(pa, vb, o[m][df]);
        }
      }
    __syncthreads();
  }

#pragma unroll
  for (int m = 0; m < 2; ++m)
#pragma unroll
    for (int df = 0; df < 4; ++df)
#pragma unroll
      for (int r = 0; r < 4; ++r) {
        const int i = qb + wave * 32 + m * 16 + hi * 4 + r;
        AV[((size_t)(b * QLEN + i)) * DMODEL + n * DH + df * 16 + lr] =
            f2h(o[m][df][r] / lrow[m][r]);
      }
}

// ---------------- launch ----------------
extern "C" void kernel_launch(void* const* d_in, const int* in_sizes, int n_in,
                              void* d_out, int out_size, void* d_ws, size_t ws_size,
                              hipStream_t stream) {
  (void)in_sizes; (void)n_in; (void)out_size; (void)ws_size;
  const float* x   = (const float*)d_in[0];
  const float* mem = (const float*)d_in[1];
  const float* pos = (const float*)d_in[2];
  // d_in[3] = attn_mask (recomputed analytically; ignored)
  const float* Wq  = (const float*)d_in[4];
  const float* Wk  = (const float*)d_in[5];
  const float* Wv  = (const float*)d_in[6];
  const float* Wr  = (const float*)d_in[7];
  const float* Wo  = (const float*)d_in[8];
  const float* rwb = (const float*)d_in[9];
  const float* rrb = (const float*)d_in[10];
  float* out = (float*)d_out;

  char* ws = (char*)d_ws;
  size_t off = 0;
  auto alloc = [&](size_t elems) {
    void* p = (void*)(ws + off);
    off += (elems * sizeof(f16) + 255) & ~(size_t)255;
    return (f16*)p;
  };
  f16* Xb  = alloc((size_t)B_SZ * QLEN * DMODEL);
  f16* Kin = alloc((size_t)B_SZ * KLEN * DMODEL);
  f16* Pos = alloc((size_t)KLEN * DMODEL);
  f16* Wqb = alloc((size_t)DMODEL * DMODEL);
  f16* Wkb = alloc((size_t)DMODEL * DMODEL);
  f16* Wvb = alloc((size_t)DMODEL * DMODEL);
  f16* Wrb = alloc((size_t)DMODEL * DMODEL);
  f16* Wob = alloc((size_t)DMODEL * DMODEL);
  f16* Qwb = alloc((size_t)B_SZ * QLEN * DMODEL);
  f16* Qrb = alloc((size_t)B_SZ * QLEN * DMODEL);
  f16* Kbb = alloc((size_t)B_SZ * KLEN * DMODEL);
  f16* Vbb = alloc((size_t)B_SZ * KLEN * DMODEL);
  f16* Rbb = alloc((size_t)KLEN * DMODEL);
  f16* AVb = alloc((size_t)B_SZ * QLEN * DMODEL);
  f16* BDb = alloc((size_t)B_SZ * NH * QLEN * KLEN);  // 128 MB

  const dim3 blk(256);
  // pack
  convert_kernel<<<dim3(B_SZ * QLEN * DMODEL / 4 / 256), blk, 0, stream>>>(
      x, Xb, B_SZ * QLEN * DMODEL / 4);
  convert_kernel<<<dim3(KLEN * DMODEL / 4 / 256), blk, 0, stream>>>(
      pos, Pos, KLEN * DMODEL / 4);
  convert_kernel<<<dim3(DMODEL * DMODEL / 4 / 256), blk, 0, stream>>>(
      Wq, Wqb, DMODEL * DMODEL / 4);
  convert_kernel<<<dim3(DMODEL * DMODEL / 4 / 256), blk, 0, stream>>>(
      Wk, Wkb, DMODEL * DMODEL / 4);
  convert_kernel<<<dim3(DMODEL * DMODEL / 4 / 256), blk, 0, stream>>>(
      Wv, Wvb, DMODEL * DMODEL / 4);
  convert_kernel<<<dim3(DMODEL * DMODEL / 4 / 256), blk, 0, stream>>>(
      Wr, Wrb, DMODEL * DMODEL / 4);
  convert_kernel<<<dim3(DMODEL * DMODEL / 4 / 256), blk, 0, stream>>>(
      Wo, Wob, DMODEL * DMODEL / 4);
  build_kin_kernel<<<dim3(B_SZ * KLEN * DMODEL / 4 / 256), blk, 0, stream>>>(x, mem, Kin);

  // projections
  gemm_bt_kernel<1, 0, 0><<<dim3(DMODEL / 128, B_SZ * QLEN / 128, 1), blk, 0, stream>>>(
      Xb, Wqb, Qwb, Qrb, rwb, rrb, B_SZ * QLEN, DMODEL, DMODEL, DMODEL, DMODEL, DMODEL);
  gemm_bt_kernel<0, 0, 0><<<dim3(DMODEL / 128, B_SZ * KLEN / 128, 1), blk, 0, stream>>>(
      Kin, Wkb, Kbb, nullptr, nullptr, nullptr, B_SZ * KLEN, DMODEL, DMODEL, DMODEL,
      DMODEL, DMODEL);
  gemm_bt_kernel<0, 0, 0><<<dim3(DMODEL / 128, B_SZ * KLEN / 128, 1), blk, 0, stream>>>(
      Kin, Wvb, Vbb, nullptr, nullptr, nullptr, B_SZ * KLEN, DMODEL, DMODEL, DMODEL,
      DMODEL, DMODEL);
  gemm_bt_kernel<0, 0, 0><<<dim3(DMODEL / 128, KLEN / 128, 1), blk, 0, stream>>>(
      Pos, Wrb, Rbb, nullptr, nullptr, nullptr, KLEN, DMODEL, DMODEL, DMODEL, DMODEL,
      DMODEL);
  // BD = Qr . R^T per (b, head): M=QLEN, N=KLEN, K=DH
  gemm_bt_kernel<0, 0, 1><<<dim3(KLEN / 128, QLEN / 128, B_SZ * NH), blk, 0, stream>>>(
      Qrb, Rbb, BDb, nullptr, nullptr, nullptr, QLEN, KLEN, DH, DMODEL, DMODEL, KLEN);
  // attention
  attn_kernel<<<dim3(QLEN / 128, NH, B_SZ), blk, 0, stream>>>(Qwb, Kbb, Vbb, BDb, AVb);
  // output projection (f32 out)
  gemm_bt_kernel<0, 1, 0><<<dim3(DMODEL / 128, B_SZ * QLEN / 128, 1), blk, 0, stream>>>(
      AVb, Wob, out, nullptr, nullptr, nullptr, B_SZ * QLEN, DMODEL, DMODEL, DMODEL,
      DMODEL, DMODEL);
}

// Round 4
// 350.104 us; speedup vs baseline: 1.6716x; 1.6716x over previous
//
#include <hip/hip_runtime.h>

// Transformer-XL relative multi-head attention, MI355X (gfx950).
// Round 3: fix graph-replay race — barrier-protect the BD LDS handoff in attn,
// remove wave-divergent skip guard. Otherwise identical to round 2.

#define B_SZ 2
#define QLEN 1024
#define MLEN 1024
#define KLEN 2048
#define DMODEL 1024
#define NH 16
#define DH 64

typedef _Float16 f16;
typedef __attribute__((ext_vector_type(8))) _Float16 f16x8;
typedef __attribute__((ext_vector_type(4))) _Float16 f16x4;
typedef __attribute__((ext_vector_type(4))) float f32x4;

__device__ __forceinline__ f16 f2h(float v) { return (f16)v; }
__device__ __forceinline__ float h2f(f16 v) { return (float)v; }

__device__ __forceinline__ f32x4 mfma16(f16x8 a, f16x8 b, f32x4 c) {
  return __builtin_amdgcn_mfma_f32_16x16x32_f16(a, b, c, 0, 0, 0);
}

// ---------------- pack ----------------
__global__ __launch_bounds__(256) void convert_kernel(const float* __restrict__ src,
                                                      f16* __restrict__ dst, int n4) {
  const int i = blockIdx.x * 256 + threadIdx.x;
  if (i >= n4) return;
  const float4 v = reinterpret_cast<const float4*>(src)[i];
  f16x4 o = {(f16)v.x, (f16)v.y, (f16)v.z, (f16)v.w};
  reinterpret_cast<f16x4*>(dst)[i] = o;
}

__global__ __launch_bounds__(256) void pack_weights_kernel(
    const float* __restrict__ Wq, const float* __restrict__ Wk,
    const float* __restrict__ Wv, const float* __restrict__ Wr,
    const float* __restrict__ Wo, f16* __restrict__ Wqb, f16* __restrict__ Wkb,
    f16* __restrict__ Wvb, f16* __restrict__ Wrb, f16* __restrict__ Wob) {
  const float* src;
  f16* dst;
  switch (blockIdx.y) {
    case 0: src = Wq; dst = Wqb; break;
    case 1: src = Wk; dst = Wkb; break;
    case 2: src = Wv; dst = Wvb; break;
    case 3: src = Wr; dst = Wrb; break;
    default: src = Wo; dst = Wob; break;
  }
  const int i = blockIdx.x * 256 + threadIdx.x;
  const float4 v = reinterpret_cast<const float4*>(src)[i];
  f16x4 o = {(f16)v.x, (f16)v.y, (f16)v.z, (f16)v.w};
  reinterpret_cast<f16x4*>(dst)[i] = o;
}

// Kin = concat(mem, x) in f16; also emits Xb (f16 copy of x).
__global__ __launch_bounds__(256) void build_kin_kernel(const float* __restrict__ x,
                                                        const float* __restrict__ mem,
                                                        f16* __restrict__ kin,
                                                        f16* __restrict__ xb) {
  const int i = blockIdx.x * 256 + threadIdx.x;  // one 4-elem chunk
  const int per_b = KLEN * DMODEL / 4;
  const int b = i / per_b;
  const int rem = i - b * per_b;
  const int row = rem / (DMODEL / 4);
  const int cc = (rem - row * (DMODEL / 4)) * 4;
  const float* src = (row < MLEN)
      ? mem + ((size_t)b * MLEN + row) * DMODEL + cc
      : x + ((size_t)b * QLEN + (row - MLEN)) * DMODEL + cc;
  const float4 v = *reinterpret_cast<const float4*>(src);
  f16x4 o = {(f16)v.x, (f16)v.y, (f16)v.z, (f16)v.w};
  *reinterpret_cast<f16x4*>(kin + (size_t)i * 4) = o;
  if (row >= MLEN)
    *reinterpret_cast<f16x4*>(&xb[((size_t)b * QLEN + (row - MLEN)) * DMODEL + cc]) = o;
}

// ---------------- batched projection GEMM: C[M,1024] = A[M,1024].W^T ----------------
// 128x128 tile, 4 waves, BK=32, padded LDS. blockIdx.y selects which projection:
//  y<16: Q (dual out +r_w_bias/+r_r_bias), y<48: K, y<80: V, else: R.
__global__ __launch_bounds__(256) void proj_kernel(
    const f16* __restrict__ Xb, const f16* __restrict__ Kin,
    const f16* __restrict__ Pos, const f16* __restrict__ Wqb,
    const f16* __restrict__ Wkb, const f16* __restrict__ Wvb,
    const f16* __restrict__ Wrb, f16* __restrict__ Qwb, f16* __restrict__ Qrb,
    f16* __restrict__ Kbb, f16* __restrict__ Vbb, f16* __restrict__ Rbb,
    const float* __restrict__ rwb, const float* __restrict__ rrb) {
  const int y = blockIdx.y;
  const f16 *A, *Bm;
  f16 *C0, *C1 = nullptr;
  int bm;
  bool dual = false;
  if (y < 16)      { A = Xb;  Bm = Wqb; C0 = Qwb; C1 = Qrb; bm = y * 128; dual = true; }
  else if (y < 48) { A = Kin; Bm = Wkb; C0 = Kbb; bm = (y - 16) * 128; }
  else if (y < 80) { A = Kin; Bm = Wvb; C0 = Vbb; bm = (y - 48) * 128; }
  else             { A = Pos; Bm = Wrb; C0 = Rbb; bm = (y - 80) * 128; }

  const int bn = blockIdx.x * 128;
  const int tid = threadIdx.x;
  const int wave = tid >> 6, lane = tid & 63;
  const int wr = wave >> 1, wc = wave & 1;
  const int lr = lane & 15, hi = lane >> 4;

  __shared__ f16 As[128][40];
  __shared__ f16 Bs[128][40];

  f32x4 acc[4][4];
#pragma unroll
  for (int m = 0; m < 4; ++m)
#pragma unroll
    for (int n = 0; n < 4; ++n) acc[m][n] = f32x4{0.f, 0.f, 0.f, 0.f};

  for (int k0 = 0; k0 < DMODEL; k0 += 32) {
#pragma unroll
    for (int it = 0; it < 2; ++it) {
      const int c = it * 256 + tid;
      const int row = c >> 2, col8 = (c & 3) << 3;
      *reinterpret_cast<f16x8*>(&As[row][col8]) =
          *reinterpret_cast<const f16x8*>(&A[(size_t)(bm + row) * DMODEL + k0 + col8]);
      *reinterpret_cast<f16x8*>(&Bs[row][col8]) =
          *reinterpret_cast<const f16x8*>(&Bm[(size_t)(bn + row) * DMODEL + k0 + col8]);
    }
    __syncthreads();
    f16x8 af[4], bf[4];
#pragma unroll
    for (int m = 0; m < 4; ++m)
      af[m] = *reinterpret_cast<const f16x8*>(&As[wr * 64 + m * 16 + lr][hi * 8]);
#pragma unroll
    for (int n = 0; n < 4; ++n)
      bf[n] = *reinterpret_cast<const f16x8*>(&Bs[wc * 64 + n * 16 + lr][hi * 8]);
#pragma unroll
    for (int m = 0; m < 4; ++m)
#pragma unroll
      for (int n = 0; n < 4; ++n) acc[m][n] = mfma16(af[m], bf[n], acc[m][n]);
    __syncthreads();
  }

#pragma unroll
  for (int m = 0; m < 4; ++m)
#pragma unroll
    for (int n = 0; n < 4; ++n)
#pragma unroll
      for (int r = 0; r < 4; ++r) {
        const int grow = bm + wr * 64 + m * 16 + hi * 4 + r;
        const int gcol = bn + wc * 64 + n * 16 + lr;
        const float v = acc[m][n][r];
        if (dual) {
          C0[(size_t)grow * DMODEL + gcol] = f2h(v + rwb[gcol]);
          C1[(size_t)grow * DMODEL + gcol] = f2h(v + rrb[gcol]);
        } else {
          C0[(size_t)grow * DMODEL + gcol] = f2h(v);
        }
      }
}

// ---------------- output projection: out[M,1024] = AV.Wo^T (f32 out) ----------------
__global__ __launch_bounds__(256) void gemm_out_kernel(const f16* __restrict__ A,
                                                       const f16* __restrict__ Bm,
                                                       float* __restrict__ C) {
  const int bm = blockIdx.y * 128, bn = blockIdx.x * 128;
  const int tid = threadIdx.x;
  const int wave = tid >> 6, lane = tid & 63;
  const int wr = wave >> 1, wc = wave & 1;
  const int lr = lane & 15, hi = lane >> 4;

  __shared__ f16 As[128][40];
  __shared__ f16 Bs[128][40];

  f32x4 acc[4][4];
#pragma unroll
  for (int m = 0; m < 4; ++m)
#pragma unroll
    for (int n = 0; n < 4; ++n) acc[m][n] = f32x4{0.f, 0.f, 0.f, 0.f};

  for (int k0 = 0; k0 < DMODEL; k0 += 32) {
#pragma unroll
    for (int it = 0; it < 2; ++it) {
      const int c = it * 256 + tid;
      const int row = c >> 2, col8 = (c & 3) << 3;
      *reinterpret_cast<f16x8*>(&As[row][col8]) =
          *reinterpret_cast<const f16x8*>(&A[(size_t)(bm + row) * DMODEL + k0 + col8]);
      *reinterpret_cast<f16x8*>(&Bs[row][col8]) =
          *reinterpret_cast<const f16x8*>(&Bm[(size_t)(bn + row) * DMODEL + k0 + col8]);
    }
    __syncthreads();
    f16x8 af[4], bf[4];
#pragma unroll
    for (int m = 0; m < 4; ++m)
      af[m] = *reinterpret_cast<const f16x8*>(&As[wr * 64 + m * 16 + lr][hi * 8]);
#pragma unroll
    for (int n = 0; n < 4; ++n)
      bf[n] = *reinterpret_cast<const f16x8*>(&Bs[wc * 64 + n * 16 + lr][hi * 8]);
#pragma unroll
    for (int m = 0; m < 4; ++m)
#pragma unroll
      for (int n = 0; n < 4; ++n) acc[m][n] = mfma16(af[m], bf[n], acc[m][n]);
    __syncthreads();
  }

#pragma unroll
  for (int m = 0; m < 4; ++m)
#pragma unroll
    for (int n = 0; n < 4; ++n)
#pragma unroll
      for (int r = 0; r < 4; ++r)
        C[(size_t)(bm + wr * 64 + m * 16 + hi * 4 + r) * DMODEL + bn + wc * 64 +
          n * 16 + lr] = acc[m][n][r];
}

// ---------------- fused attention ----------------
// Block: 512 threads = 8 waves; block owns (b, head, 128 q-rows); wave owns 16 rows.
// Per 64-key tile: stage K (row-major) + V^T in LDS; S = Qw.K^T (MFMA from LDS);
// BDu = Qr.R_window^T (MFMA, R rows clamped — clamp region == masked region);
// BDu written PRE-SHIFTED to per-wave LDS; __syncthreads(); S += BD, scale, mask;
// online softmax; P -> same per-wave LDS (round-0-proven same-wave handoff);
// O += P.V (MFMA). Uniform control flow; 3 barriers per tile.
__global__ __launch_bounds__(512) void attn_kernel(
    const f16* __restrict__ Qw, const f16* __restrict__ Qr,
    const f16* __restrict__ Kb, const f16* __restrict__ Vb,
    const f16* __restrict__ Rb, f16* __restrict__ AV) {
  const int qb = blockIdx.x * 128;
  const int n = blockIdx.y;
  const int b = blockIdx.z;
  const int tid = threadIdx.x;
  const int wave = tid >> 6, lane = tid & 63;
  const int lr = lane & 15, hi = lane >> 4;
  const int w0 = qb + wave * 16;  // first (global) q row of this wave

  __shared__ f16 Ks[64][72];      // [j][d]
  __shared__ f16 Vs[64][72];      // transposed: [d][j]
  __shared__ f16 PB[8][16][72];   // per-wave: shifted-BD tile, then P tile

  // Q fragments (A-layout, M=16): row = lr, col = kk*32 + hi*8
  f16x8 qw[2], qr[2];
  {
    const size_t qbase = ((size_t)(b * QLEN + w0 + lr)) * DMODEL + n * DH;
#pragma unroll
    for (int kk = 0; kk < 2; ++kk) {
      qw[kk] = *reinterpret_cast<const f16x8*>(&Qw[qbase + kk * 32 + hi * 8]);
      qr[kk] = *reinterpret_cast<const f16x8*>(&Qr[qbase + kk * 32 + hi * 8]);
    }
  }

  f32x4 o[4];
#pragma unroll
  for (int df = 0; df < 4; ++df) o[df] = f32x4{0.f, 0.f, 0.f, 0.f};
  float mrow[4], lrow[4];
#pragma unroll
  for (int r = 0; r < 4; ++r) { mrow[r] = -1e30f; lrow[r] = 0.f; }

  const f16* Rn = Rb + n * DH;
  const int jtiles = (qb + 128 + MLEN) >> 6;

  for (int jt = 0; jt < jtiles; ++jt) {
    const int j0 = jt << 6;
    const size_t kvbase = ((size_t)(b * KLEN + j0)) * DMODEL + n * DH;
    {
      const int c = tid;
      const int krow = c >> 3, kcol8 = (c & 7) << 3;
      *reinterpret_cast<f16x8*>(&Ks[krow][kcol8]) =
          *reinterpret_cast<const f16x8*>(&Kb[kvbase + (size_t)krow * DMODEL + kcol8]);
      const int vrow = c & 63, vcol8 = ((c >> 6) & 7) << 3;
      const f16x8 vv =
          *reinterpret_cast<const f16x8*>(&Vb[kvbase + (size_t)vrow * DMODEL + vcol8]);
#pragma unroll
      for (int e = 0; e < 8; ++e) Vs[vcol8 + e][vrow] = vv[e];
    }
    __syncthreads();

    // S = Qw . K^T
    f32x4 s[4];
#pragma unroll
    for (int nf = 0; nf < 4; ++nf) s[nf] = f32x4{0.f, 0.f, 0.f, 0.f};
#pragma unroll
    for (int kk = 0; kk < 2; ++kk)
#pragma unroll
      for (int nf = 0; nf < 4; ++nf) {
        const f16x8 kf =
            *reinterpret_cast<const f16x8*>(&Ks[nf * 16 + lr][kk * 32 + hi * 8]);
        s[nf] = mfma16(qw[kk], kf, s[nf]);
      }

    // BDu = Qr . R_window^T over u in [u0, u0+80); u >= KLEN <=> masked (clamp ok)
    const int u0 = j0 + QLEN - 16 - w0;  // 16-aligned, >= 0
    f32x4 bd[5];
#pragma unroll
    for (int nt = 0; nt < 5; ++nt) bd[nt] = f32x4{0.f, 0.f, 0.f, 0.f};
#pragma unroll
    for (int nt = 0; nt < 5; ++nt) {
      const int u = u0 + nt * 16 + lr;
      const int uc = u < KLEN ? u : KLEN - 1;
#pragma unroll
      for (int kk = 0; kk < 2; ++kk) {
        const f16x8 rf = *reinterpret_cast<const f16x8*>(
            &Rn[(size_t)uc * DMODEL + kk * 32 + hi * 8]);
        bd[nt] = mfma16(qr[kk], rf, bd[nt]);
      }
    }

    // write shifted BD: element (t = hi*4+r, u_local = nt*16+lr) -> jl = u_local-15+t
    const int t0 = hi * 4;
#pragma unroll
    for (int nt = 0; nt < 5; ++nt)
#pragma unroll
      for (int r = 0; r < 4; ++r) {
        const int jl = nt * 16 + lr - 15 + t0 + r;
        if (jl >= 0 && jl < 64) PB[wave][t0 + r][jl] = f2h(bd[nt][r]);
      }
    __syncthreads();  // barrier-protect the BD handoff (graph-replay race fix)

    float sv[4][4];
#pragma unroll
    for (int r = 0; r < 4; ++r) {
      const int i = w0 + t0 + r;
#pragma unroll
      for (int nf = 0; nf < 4; ++nf) {
        const int j = j0 + nf * 16 + lr;
        sv[nf][r] = (j <= i + MLEN)
                        ? (s[nf][r] + h2f(PB[wave][t0 + r][nf * 16 + lr])) * 0.125f
                        : -1e30f;
      }
    }

    // online softmax, 4 rows per thread, rows live on 16 lanes (lr)
#pragma unroll
    for (int r = 0; r < 4; ++r) {
      float tmax = fmaxf(fmaxf(sv[0][r], sv[1][r]), fmaxf(sv[2][r], sv[3][r]));
#pragma unroll
      for (int d = 1; d < 16; d <<= 1) tmax = fmaxf(tmax, __shfl_xor(tmax, d, 64));
      const float mnew = fmaxf(mrow[r], tmax);
      const float alpha = __expf(mrow[r] - mnew);
      mrow[r] = mnew;
      float tsum = 0.f;
#pragma unroll
      for (int nf = 0; nf < 4; ++nf) {
        const float p = __expf(sv[nf][r] - mnew);
        sv[nf][r] = p;
        tsum += p;
      }
#pragma unroll
      for (int d = 1; d < 16; d <<= 1) tsum += __shfl_xor(tsum, d, 64);
      lrow[r] = lrow[r] * alpha + tsum;
#pragma unroll
      for (int df = 0; df < 4; ++df) o[df][r] *= alpha;
    }

    // P -> per-wave LDS (read-then-overwrite of PB is same-wave WAR; the
    // write->read below is the round-0-proven same-wave handoff)
#pragma unroll
    for (int nf = 0; nf < 4; ++nf)
#pragma unroll
      for (int r = 0; r < 4; ++r) PB[wave][t0 + r][nf * 16 + lr] = f2h(sv[nf][r]);

    // O += P . V
#pragma unroll
    for (int kk = 0; kk < 2; ++kk) {
      const f16x8 pa =
          *reinterpret_cast<const f16x8*>(&PB[wave][lr][kk * 32 + hi * 8]);
#pragma unroll
      for (int df = 0; df < 4; ++df) {
        const f16x8 vb =
            *reinterpret_cast<const f16x8*>(&Vs[df * 16 + lr][kk * 32 + hi * 8]);
        o[df] = mfma16(pa, vb, o[df]);
      }
    }
    __syncthreads();
  }

#pragma unroll
  for (int df = 0; df < 4; ++df)
#pragma unroll
    for (int r = 0; r < 4; ++r) {
      const int i = w0 + hi * 4 + r;
      AV[((size_t)(b * QLEN + i)) * DMODEL + n * DH + df * 16 + lr] =
          f2h(o[df][r] / lrow[r]);
    }
}

// ---------------- launch ----------------
extern "C" void kernel_launch(void* const* d_in, const int* in_sizes, int n_in,
                              void* d_out, int out_size, void* d_ws, size_t ws_size,
                              hipStream_t stream) {
  (void)in_sizes; (void)n_in; (void)out_size; (void)ws_size;
  const float* x   = (const float*)d_in[0];
  const float* mem = (const float*)d_in[1];
  const float* pos = (const float*)d_in[2];
  // d_in[3] = attn_mask (recomputed analytically; ignored)
  const float* Wq  = (const float*)d_in[4];
  const float* Wk  = (const float*)d_in[5];
  const float* Wv  = (const float*)d_in[6];
  const float* Wr  = (const float*)d_in[7];
  const float* Wo  = (const float*)d_in[8];
  const float* rwb = (const float*)d_in[9];
  const float* rrb = (const float*)d_in[10];
  float* out = (float*)d_out;

  char* ws = (char*)d_ws;
  size_t off = 0;
  auto alloc = [&](size_t elems) {
    void* p = (void*)(ws + off);
    off += (elems * sizeof(f16) + 255) & ~(size_t)255;
    return (f16*)p;
  };
  f16* Xb  = alloc((size_t)B_SZ * QLEN * DMODEL);
  f16* Kin = alloc((size_t)B_SZ * KLEN * DMODEL);
  f16* Pos = alloc((size_t)KLEN * DMODEL);
  f16* Wqb = alloc((size_t)DMODEL * DMODEL);
  f16* Wkb = alloc((size_t)DMODEL * DMODEL);
  f16* Wvb = alloc((size_t)DMODEL * DMODEL);
  f16* Wrb = alloc((size_t)DMODEL * DMODEL);
  f16* Wob = alloc((size_t)DMODEL * DMODEL);
  f16* Qwb = alloc((size_t)B_SZ * QLEN * DMODEL);
  f16* Qrb = alloc((size_t)B_SZ * QLEN * DMODEL);
  f16* Kbb = alloc((size_t)B_SZ * KLEN * DMODEL);
  f16* Vbb = alloc((size_t)B_SZ * KLEN * DMODEL);
  f16* Rbb = alloc((size_t)KLEN * DMODEL);
  f16* AVb = alloc((size_t)B_SZ * QLEN * DMODEL);

  // pack (3 launches)
  pack_weights_kernel<<<dim3(1024, 5), dim3(256), 0, stream>>>(
      Wq, Wk, Wv, Wr, Wo, Wqb, Wkb, Wvb, Wrb, Wob);
  convert_kernel<<<dim3(KLEN * DMODEL / 4 / 256), dim3(256), 0, stream>>>(
      pos, Pos, KLEN * DMODEL / 4);
  build_kin_kernel<<<dim3(B_SZ * KLEN * DMODEL / 4 / 256), dim3(256), 0, stream>>>(
      x, mem, Kin, Xb);

  // all projections in one dispatch: y-blocks = 16(Q) + 32(K) + 32(V) + 16(R)
  proj_kernel<<<dim3(8, 96), dim3(256), 0, stream>>>(
      Xb, Kin, Pos, Wqb, Wkb, Wvb, Wrb, Qwb, Qrb, Kbb, Vbb, Rbb, rwb, rrb);

  // fused attention (BD computed in-kernel)
  attn_kernel<<<dim3(QLEN / 128, NH, B_SZ), dim3(512), 0, stream>>>(
      Qwb, Qrb, Kbb, Vbb, Rbb, AVb);

  // output projection (f32 out)
  gemm_out_kernel<<<dim3(DMODEL / 128, B_SZ * QLEN / 128), dim3(256), 0, stream>>>(
      AVb, Wob, out);
}

// Round 5
// 281.167 us; speedup vs baseline: 2.0814x; 1.2452x over previous
//
#include <hip/hip_runtime.h>

// Transformer-XL relative multi-head attention, MI355X (gfx950).
// Round 4: attn j-split (2x blocks, same traffic) + T14 async staging +
// bpermute rel-shift (no BD LDS round-trip, 2 barriers/tile);
// proj/out GEMMs -> m97 structure (global_load_lds + XOR-swizzled LDS).

#define B_SZ 2
#define QLEN 1024
#define MLEN 1024
#define KLEN 2048
#define DMODEL 1024
#define NH 16
#define DH 64

typedef _Float16 f16;
typedef __attribute__((ext_vector_type(8))) _Float16 f16x8;
typedef __attribute__((ext_vector_type(4))) _Float16 f16x4;
typedef __attribute__((ext_vector_type(4))) float f32x4;

__device__ __forceinline__ f16 f2h(float v) { return (f16)v; }
__device__ __forceinline__ float h2f(f16 v) { return (float)v; }

__device__ __forceinline__ f32x4 mfma16(f16x8 a, f16x8 b, f32x4 c) {
  return __builtin_amdgcn_mfma_f32_16x16x32_f16(a, b, c, 0, 0, 0);
}

__device__ __forceinline__ void gload_lds16(const f16* g, f16* l) {
  __builtin_amdgcn_global_load_lds(
      (const __attribute__((address_space(1))) void*)g,
      (__attribute__((address_space(3))) void*)l, 16, 0, 0);
}

__device__ __forceinline__ float bperm(int srclane, float v) {
  return __int_as_float(
      __builtin_amdgcn_ds_bpermute(srclane << 2, __float_as_int(v)));
}

// ---------------- pack ----------------
__global__ __launch_bounds__(256) void convert_kernel(const float* __restrict__ src,
                                                      f16* __restrict__ dst, int n4) {
  const int i = blockIdx.x * 256 + threadIdx.x;
  if (i >= n4) return;
  const float4 v = reinterpret_cast<const float4*>(src)[i];
  f16x4 o = {(f16)v.x, (f16)v.y, (f16)v.z, (f16)v.w};
  reinterpret_cast<f16x4*>(dst)[i] = o;
}

__global__ __launch_bounds__(256) void pack_weights_kernel(
    const float* __restrict__ Wq, const float* __restrict__ Wk,
    const float* __restrict__ Wv, const float* __restrict__ Wr,
    const float* __restrict__ Wo, f16* __restrict__ Wqb, f16* __restrict__ Wkb,
    f16* __restrict__ Wvb, f16* __restrict__ Wrb, f16* __restrict__ Wob) {
  const float* src;
  f16* dst;
  switch (blockIdx.y) {
    case 0: src = Wq; dst = Wqb; break;
    case 1: src = Wk; dst = Wkb; break;
    case 2: src = Wv; dst = Wvb; break;
    case 3: src = Wr; dst = Wrb; break;
    default: src = Wo; dst = Wob; break;
  }
  const int i = blockIdx.x * 256 + threadIdx.x;
  const float4 v = reinterpret_cast<const float4*>(src)[i];
  f16x4 o = {(f16)v.x, (f16)v.y, (f16)v.z, (f16)v.w};
  reinterpret_cast<f16x4*>(dst)[i] = o;
}

__global__ __launch_bounds__(256) void build_kin_kernel(const float* __restrict__ x,
                                                        const float* __restrict__ mem,
                                                        f16* __restrict__ kin,
                                                        f16* __restrict__ xb) {
  const int i = blockIdx.x * 256 + threadIdx.x;
  const int per_b = KLEN * DMODEL / 4;
  const int b = i / per_b;
  const int rem = i - b * per_b;
  const int row = rem / (DMODEL / 4);
  const int cc = (rem - row * (DMODEL / 4)) * 4;
  const float* src = (row < MLEN)
      ? mem + ((size_t)b * MLEN + row) * DMODEL + cc
      : x + ((size_t)b * QLEN + (row - MLEN)) * DMODEL + cc;
  const float4 v = *reinterpret_cast<const float4*>(src);
  f16x4 o = {(f16)v.x, (f16)v.y, (f16)v.z, (f16)v.w};
  *reinterpret_cast<f16x4*>(kin + (size_t)i * 4) = o;
  if (row >= MLEN)
    *reinterpret_cast<f16x4*>(&xb[((size_t)b * QLEN + (row - MLEN)) * DMODEL + cc]) = o;
}

// ------------- GEMM core (m97 structure): C[M,1024] = A[M,1024].B[1024,1024]^T -------
// 128x128 tile, 4 waves, BK=64, linear LDS + both-sides XOR swizzle (T2/rule21):
// LDS[row][c16] holds global[row][c16 ^ (row&7)]; reads XOR the same mask.
template <int DUAL, int OUT_F32>
__device__ __forceinline__ void gemm_core(const f16* __restrict__ A,
                                          const f16* __restrict__ Bm,
                                          void* __restrict__ C0v,
                                          void* __restrict__ C1v,
                                          const float* __restrict__ bias0,
                                          const float* __restrict__ bias1, int bm,
                                          int bn) {
  const int tid = threadIdx.x;
  const int wave = tid >> 6, lane = tid & 63;
  const int wr = wave >> 1, wc = wave & 1;
  const int lr = lane & 15, hi = lane >> 4;

  __shared__ f16 As[128 * 64];
  __shared__ f16 Bs[128 * 64];

  f32x4 acc[4][4];
#pragma unroll
  for (int m = 0; m < 4; ++m)
#pragma unroll
    for (int n = 0; n < 4; ++n) acc[m][n] = f32x4{0.f, 0.f, 0.f, 0.f};

  for (int k0 = 0; k0 < DMODEL; k0 += 64) {
    __syncthreads();  // previous iteration's reads complete
#pragma unroll
    for (int it = 0; it < 4; ++it) {
      const int c = it * 256 + tid;          // chunk: (row, c16)
      const int row = c >> 3, c16 = c & 7;
      const int c16s = c16 ^ (row & 7);      // pre-swizzled source
      gload_lds16(&A[(size_t)(bm + row) * DMODEL + k0 + c16s * 8], &As[c * 8]);
      gload_lds16(&Bm[(size_t)(bn + row) * DMODEL + k0 + c16s * 8], &Bs[c * 8]);
    }
    __syncthreads();  // drains vmcnt (compiler) — staged tile visible
#pragma unroll
    for (int kk = 0; kk < 2; ++kk) {
      f16x8 af[4], bf[4];
#pragma unroll
      for (int m = 0; m < 4; ++m) {
        const int row = wr * 64 + m * 16 + lr;
        const int colf = (kk * 32 + hi * 8) ^ ((row & 7) << 3);
        af[m] = *reinterpret_cast<const f16x8*>(&As[row * 64 + colf]);
      }
#pragma unroll
      for (int n = 0; n < 4; ++n) {
        const int row = wc * 64 + n * 16 + lr;
        const int colf = (kk * 32 + hi * 8) ^ ((row & 7) << 3);
        bf[n] = *reinterpret_cast<const f16x8*>(&Bs[row * 64 + colf]);
      }
#pragma unroll
      for (int m = 0; m < 4; ++m)
#pragma unroll
        for (int n = 0; n < 4; ++n) acc[m][n] = mfma16(af[m], bf[n], acc[m][n]);
    }
  }

#pragma unroll
  for (int m = 0; m < 4; ++m)
#pragma unroll
    for (int n = 0; n < 4; ++n)
#pragma unroll
      for (int r = 0; r < 4; ++r) {
        const int grow = bm + wr * 64 + m * 16 + hi * 4 + r;
        const int gcol = bn + wc * 64 + n * 16 + lr;
        const float v = acc[m][n][r];
        if constexpr (OUT_F32) {
          reinterpret_cast<float*>(C0v)[(size_t)grow * DMODEL + gcol] = v;
        } else if constexpr (DUAL) {
          reinterpret_cast<f16*>(C0v)[(size_t)grow * DMODEL + gcol] =
              f2h(v + bias0[gcol]);
          reinterpret_cast<f16*>(C1v)[(size_t)grow * DMODEL + gcol] =
              f2h(v + bias1[gcol]);
        } else {
          reinterpret_cast<f16*>(C0v)[(size_t)grow * DMODEL + gcol] = f2h(v);
        }
      }
}

// y<16: Q (dual +r_w_bias/+r_r_bias), y<48: K, y<80: V, else R.
__global__ __launch_bounds__(256) void proj_kernel(
    const f16* __restrict__ Xb, const f16* __restrict__ Kin,
    const f16* __restrict__ Pos, const f16* __restrict__ Wqb,
    const f16* __restrict__ Wkb, const f16* __restrict__ Wvb,
    const f16* __restrict__ Wrb, f16* __restrict__ Qwb, f16* __restrict__ Qrb,
    f16* __restrict__ Kbb, f16* __restrict__ Vbb, f16* __restrict__ Rbb,
    const float* __restrict__ rwb, const float* __restrict__ rrb) {
  const int y = blockIdx.y;
  const int bn = blockIdx.x * 128;
  if (y < 16) {
    gemm_core<1, 0>(Xb, Wqb, Qwb, Qrb, rwb, rrb, y * 128, bn);
  } else if (y < 48) {
    gemm_core<0, 0>(Kin, Wkb, Kbb, nullptr, nullptr, nullptr, (y - 16) * 128, bn);
  } else if (y < 80) {
    gemm_core<0, 0>(Kin, Wvb, Vbb, nullptr, nullptr, nullptr, (y - 48) * 128, bn);
  } else {
    gemm_core<0, 0>(Pos, Wrb, Rbb, nullptr, nullptr, nullptr, (y - 80) * 128, bn);
  }
}

__global__ __launch_bounds__(256) void gemm_out_kernel(const f16* __restrict__ A,
                                                       const f16* __restrict__ Bm,
                                                       float* __restrict__ C) {
  gemm_core<0, 1>(A, Bm, C, nullptr, nullptr, nullptr, blockIdx.y * 128,
                  blockIdx.x * 128);
}

// ---------------- fused attention (j-split halves) ----------------
// Block: 512 thr = 8 waves x 16 q-rows; blockIdx.x = (q-block, half).
// Per 64-key tile: T14 split staging (issue next loads -> compute -> barrier ->
// LDS commit -> barrier); S = Qw.K^T; BD = Qr.R_win^T rel-shifted via ds_bpermute
// (register-only); online softmax; P->per-wave LDS (round-0-proven); O += P.V.
// Emits unnormalized O (f32) + (m,l) per half; combine_kernel merges.
__global__ __launch_bounds__(512) void attn_kernel(
    const f16* __restrict__ Qw, const f16* __restrict__ Qr,
    const f16* __restrict__ Kb, const f16* __restrict__ Vb,
    const f16* __restrict__ Rb, float* __restrict__ Opart,
    float2* __restrict__ MLp) {
  const int qi = blockIdx.x >> 1, half = blockIdx.x & 1;
  const int qb = qi * 128;
  const int n = blockIdx.y;
  const int b = blockIdx.z;
  const int tid = threadIdx.x;
  const int wave = tid >> 6, lane = tid & 63;
  const int lr = lane & 15, hi = lane >> 4;
  const int t0 = hi * 4;
  const int w0 = qb + wave * 16;

  const int T = (qb + 128 + MLEN) >> 6;  // always even
  const int jt_beg = half ? (T >> 1) : 0;
  const int jt_end = half ? T : (T >> 1);

  __shared__ f16 Ks[64][72];
  __shared__ f16 Vs[64][72];
  __shared__ f16 Ps[8][16][72];

  f16x8 qw[2], qr[2];
  {
    const size_t qbase = ((size_t)(b * QLEN + w0 + lr)) * DMODEL + n * DH;
#pragma unroll
    for (int kk = 0; kk < 2; ++kk) {
      qw[kk] = *reinterpret_cast<const f16x8*>(&Qw[qbase + kk * 32 + hi * 8]);
      qr[kk] = *reinterpret_cast<const f16x8*>(&Qr[qbase + kk * 32 + hi * 8]);
    }
  }

  f32x4 o[4];
#pragma unroll
  for (int df = 0; df < 4; ++df) o[df] = f32x4{0.f, 0.f, 0.f, 0.f};
  float mrow[4], lrow[4];
#pragma unroll
  for (int r = 0; r < 4; ++r) { mrow[r] = -1e30f; lrow[r] = 0.f; }

  const f16* Rn = Rb + n * DH;

  // staging registers + helpers
  const int krow = tid >> 3, kc8 = (tid & 7) << 3;
  const int vrow = tid & 63, vc8 = ((tid >> 6) & 7) << 3;
  f16x8 kreg, vreg;
  auto issue = [&](int jt) {
    const size_t kvb = ((size_t)(b * KLEN + (jt << 6))) * DMODEL + n * DH;
    kreg = *reinterpret_cast<const f16x8*>(&Kb[kvb + (size_t)krow * DMODEL + kc8]);
    vreg = *reinterpret_cast<const f16x8*>(&Vb[kvb + (size_t)vrow * DMODEL + vc8]);
  };
  auto commit = [&]() {
    *reinterpret_cast<f16x8*>(&Ks[krow][kc8]) = kreg;
#pragma unroll
    for (int e = 0; e < 8; ++e) Vs[vc8 + e][vrow] = vreg[e];
  };

  issue(jt_beg);
  commit();
  __syncthreads();

  for (int jt = jt_beg; jt < jt_end; ++jt) {
    const bool hn = (jt + 1 < jt_end);
    if (hn) issue(jt + 1);  // loads in flight during compute (T14)

    const int j0 = jt << 6;

    // S = Qw . K^T
    f32x4 s[4];
#pragma unroll
    for (int nf = 0; nf < 4; ++nf) s[nf] = f32x4{0.f, 0.f, 0.f, 0.f};
#pragma unroll
    for (int kk = 0; kk < 2; ++kk)
#pragma unroll
      for (int nf = 0; nf < 4; ++nf) {
        const f16x8 kf =
            *reinterpret_cast<const f16x8*>(&Ks[nf * 16 + lr][kk * 32 + hi * 8]);
        s[nf] = mfma16(qw[kk], kf, s[nf]);
      }

    // BD over u in [u0, u0+80); clamp region == masked region
    const int u0 = j0 + QLEN - 16 - w0;  // >= 0, 16-aligned
    f32x4 bd[5];
#pragma unroll
    for (int nt = 0; nt < 5; ++nt) bd[nt] = f32x4{0.f, 0.f, 0.f, 0.f};
#pragma unroll
    for (int nt = 0; nt < 5; ++nt) {
      const int u = u0 + nt * 16 + lr;
      const int uc = u < KLEN ? u : KLEN - 1;
#pragma unroll
      for (int kk = 0; kk < 2; ++kk) {
        const f16x8 rf = *reinterpret_cast<const f16x8*>(
            &Rn[(size_t)uc * DMODEL + kk * 32 + hi * 8]);
        bd[nt] = mfma16(qr[kk], rf, bd[nt]);
      }
    }

    // rel-shift via bpermute: slot (t=t0+r, j_local) needs u_local = j_local+15-t
#pragma unroll
    for (int r = 0; r < 4; ++r) {
      const int off = 15 - t0 - r;           // uniform within hi-group
      const int sl = lr + off;               // 0..30
      const int srclane = hi * 16 + (sl & 15);
      const bool cross = sl >= 16;
      const int i = w0 + t0 + r;
#pragma unroll
      for (int nf = 0; nf < 4; ++nf) {
        const float x0 = bperm(srclane, bd[nf][r]);
        const float x1 = bperm(srclane, bd[nf + 1][r]);
        const float bv = cross ? x1 : x0;
        const int j = j0 + nf * 16 + lr;
        s[nf][r] = (j <= i + MLEN) ? (s[nf][r] + bv) * 0.125f : -1e30f;
      }
    }

    // online softmax (rows on 16 lanes sharing hi)
#pragma unroll
    for (int r = 0; r < 4; ++r) {
      float tmax = fmaxf(fmaxf(s[0][r], s[1][r]), fmaxf(s[2][r], s[3][r]));
#pragma unroll
      for (int d = 1; d < 16; d <<= 1) tmax = fmaxf(tmax, __shfl_xor(tmax, d, 64));
      const float mnew = fmaxf(mrow[r], tmax);
      const float alpha = __expf(mrow[r] - mnew);
      mrow[r] = mnew;
      float tsum = 0.f;
#pragma unroll
      for (int nf = 0; nf < 4; ++nf) {
        const float p = __expf(s[nf][r] - mnew);
        s[nf][r] = p;
        tsum += p;
      }
#pragma unroll
      for (int d = 1; d < 16; d <<= 1) tsum += __shfl_xor(tsum, d, 64);
      lrow[r] = lrow[r] * alpha + tsum;
#pragma unroll
      for (int df = 0; df < 4; ++df) o[df][r] *= alpha;
    }

    // P -> per-wave LDS (same-wave handoff, proven barrier-free)
#pragma unroll
    for (int nf = 0; nf < 4; ++nf)
#pragma unroll
      for (int r = 0; r < 4; ++r) Ps[wave][t0 + r][nf * 16 + lr] = f2h(s[nf][r]);

#pragma unroll
    for (int kk = 0; kk < 2; ++kk) {
      const f16x8 pa =
          *reinterpret_cast<const f16x8*>(&Ps[wave][lr][kk * 32 + hi * 8]);
#pragma unroll
      for (int df = 0; df < 4; ++df) {
        const f16x8 vb =
            *reinterpret_cast<const f16x8*>(&Vs[df * 16 + lr][kk * 32 + hi * 8]);
        o[df] = mfma16(pa, vb, o[df]);
      }
    }

    __syncthreads();        // all LDS reads of this tile done
    if (hn) commit();       // waitcnt on kreg/vreg inserted here by compiler
    __syncthreads();
  }

  // partial outputs (unnormalized) + m/l
  const size_t obase =
      (((size_t)(half * B_SZ + b) * NH + n) * QLEN + w0 + t0) * DH;
#pragma unroll
  for (int df = 0; df < 4; ++df)
#pragma unroll
    for (int r = 0; r < 4; ++r)
      Opart[obase + (size_t)r * DH + df * 16 + lr] = o[df][r];
  if (lr == 0) {
    const size_t mbase = ((size_t)(half * B_SZ + b) * NH + n) * QLEN + w0 + t0;
#pragma unroll
    for (int r = 0; r < 4; ++r) MLp[mbase + r] = float2{mrow[r], lrow[r]};
  }
}

__global__ __launch_bounds__(256) void combine_kernel(const float* __restrict__ Op,
                                                      const float2* __restrict__ ML,
                                                      f16* __restrict__ AV) {
  const int idx = blockIdx.x * 256 + threadIdx.x;  // (b,n,i,d4)
  const int d4 = idx & 15;
  const int i = (idx >> 4) & 1023;
  const int n = (idx >> 14) & 15;
  const int b = idx >> 18;
  const size_t r0 = ((size_t)(b * NH + n)) * QLEN + i;
  const size_t r1 = ((size_t)((B_SZ + b) * NH + n)) * QLEN + i;
  const float2 ml0 = ML[r0], ml1 = ML[r1];
  const float M = fmaxf(ml0.x, ml1.x);
  const float e0 = __expf(ml0.x - M), e1 = __expf(ml1.x - M);
  const float inv = 1.f / (ml0.y * e0 + ml1.y * e1);
  const float4 o0 = *reinterpret_cast<const float4*>(&Op[r0 * DH + d4 * 4]);
  const float4 o1 = *reinterpret_cast<const float4*>(&Op[r1 * DH + d4 * 4]);
  f16x4 out;
  out[0] = f2h((o0.x * e0 + o1.x * e1) * inv);
  out[1] = f2h((o0.y * e0 + o1.y * e1) * inv);
  out[2] = f2h((o0.z * e0 + o1.z * e1) * inv);
  out[3] = f2h((o0.w * e0 + o1.w * e1) * inv);
  *reinterpret_cast<f16x4*>(&AV[((size_t)(b * QLEN + i)) * DMODEL + n * DH + d4 * 4]) =
      out;
}

// ---------------- launch ----------------
extern "C" void kernel_launch(void* const* d_in, const int* in_sizes, int n_in,
                              void* d_out, int out_size, void* d_ws, size_t ws_size,
                              hipStream_t stream) {
  (void)in_sizes; (void)n_in; (void)out_size; (void)ws_size;
  const float* x   = (const float*)d_in[0];
  const float* mem = (const float*)d_in[1];
  const float* pos = (const float*)d_in[2];
  const float* Wq  = (const float*)d_in[4];
  const float* Wk  = (const float*)d_in[5];
  const float* Wv  = (const float*)d_in[6];
  const float* Wr  = (const float*)d_in[7];
  const float* Wo  = (const float*)d_in[8];
  const float* rwb = (const float*)d_in[9];
  const float* rrb = (const float*)d_in[10];
  float* out = (float*)d_out;

  char* ws = (char*)d_ws;
  size_t off = 0;
  auto alloc = [&](size_t bytes) {
    void* p = (void*)(ws + off);
    off += (bytes + 255) & ~(size_t)255;
    return p;
  };
  f16* Xb  = (f16*)alloc((size_t)B_SZ * QLEN * DMODEL * 2);
  f16* Kin = (f16*)alloc((size_t)B_SZ * KLEN * DMODEL * 2);
  f16* Pos = (f16*)alloc((size_t)KLEN * DMODEL * 2);
  f16* Wqb = (f16*)alloc((size_t)DMODEL * DMODEL * 2);
  f16* Wkb = (f16*)alloc((size_t)DMODEL * DMODEL * 2);
  f16* Wvb = (f16*)alloc((size_t)DMODEL * DMODEL * 2);
  f16* Wrb = (f16*)alloc((size_t)DMODEL * DMODEL * 2);
  f16* Wob = (f16*)alloc((size_t)DMODEL * DMODEL * 2);
  f16* Qwb = (f16*)alloc((size_t)B_SZ * QLEN * DMODEL * 2);
  f16* Qrb = (f16*)alloc((size_t)B_SZ * QLEN * DMODEL * 2);
  f16* Kbb = (f16*)alloc((size_t)B_SZ * KLEN * DMODEL * 2);
  f16* Vbb = (f16*)alloc((size_t)B_SZ * KLEN * DMODEL * 2);
  f16* Rbb = (f16*)alloc((size_t)KLEN * DMODEL * 2);
  f16* AVb = (f16*)alloc((size_t)B_SZ * QLEN * DMODEL * 2);
  float*  Opart = (float*)alloc((size_t)2 * B_SZ * NH * QLEN * DH * 4);
  float2* MLp   = (float2*)alloc((size_t)2 * B_SZ * NH * QLEN * 8);

  pack_weights_kernel<<<dim3(1024, 5), dim3(256), 0, stream>>>(
      Wq, Wk, Wv, Wr, Wo, Wqb, Wkb, Wvb, Wrb, Wob);
  convert_kernel<<<dim3(KLEN * DMODEL / 4 / 256), dim3(256), 0, stream>>>(
      pos, Pos, KLEN * DMODEL / 4);
  build_kin_kernel<<<dim3(B_SZ * KLEN * DMODEL / 4 / 256), dim3(256), 0, stream>>>(
      x, mem, Kin, Xb);

  proj_kernel<<<dim3(8, 96), dim3(256), 0, stream>>>(
      Xb, Kin, Pos, Wqb, Wkb, Wvb, Wrb, Qwb, Qrb, Kbb, Vbb, Rbb, rwb, rrb);

  attn_kernel<<<dim3(QLEN / 128 * 2, NH, B_SZ), dim3(512), 0, stream>>>(
      Qwb, Qrb, Kbb, Vbb, Rbb, Opart, MLp);

  combine_kernel<<<dim3(B_SZ * NH * QLEN * (DH / 4) / 256), dim3(256), 0, stream>>>(
      Opart, MLp, AVb);

  gemm_out_kernel<<<dim3(DMODEL / 128, B_SZ * QLEN / 128), dim3(256), 0, stream>>>(
      AVb, Wob, out);
}